// Round 4
// baseline (278.884 us; speedup 1.0000x reference)
//
#include <hip/hip_runtime.h>

// ---------------------------------------------------------------------------
// MultiHeadAttention fwd: B=2, S=2048, E=1024, H=16, D=64, fp32 in/out,
// bf16 MFMA compute (fp32 accum), exp2-domain online softmax.
// ---------------------------------------------------------------------------

#define SEQ   2048
#define EMB   1024
#define NHEAD 16
#define HDIM  64
#define NTOK  4096   // B*S

typedef __attribute__((ext_vector_type(8))) __bf16 bf16x8;
typedef __attribute__((ext_vector_type(4))) float  f32x4;

// workspace layout (ushort elements). top = 29360128 ushorts = 56 MB.
#define OFF_XV  0u          // [4096][1024] bf16 (value)
#define OFF_XK  4194304u
#define OFF_XQ  8388608u
#define OFF_WV  12582912u   // [1024][1024] bf16
#define OFF_WK  13631488u
#define OFF_WQ  14680064u
#define OFF_WO  15728640u
#define OFF_VB  16777216u   // [BH][S][D] bf16
#define OFF_KB  20971520u
#define OFF_QB  25165824u   // pre-scaled by 0.125*log2(e)
#define OFF_VT  4194304u    // [BH][D][S] bf16 — aliases XK (dead after projections)
#define OFF_ATT 0u          // attn out [B,S,E] — aliases XV (dead after projections)

typedef __attribute__((address_space(1))) void g_void;
typedef __attribute__((address_space(3))) void l_void;

__device__ __forceinline__ void async_cp16(const void* g, void* l) {
  // 16B per lane, dest = wave-uniform base + lane*16 (linear LDS, rule #21).
  __builtin_amdgcn_global_load_lds((g_void*)(void*)g, (l_void*)l, 16, 0, 0);
}

__device__ __forceinline__ unsigned short f2bf(float f) {
  __bf16 h = (__bf16)f;
  return __builtin_bit_cast(unsigned short, h);
}

__device__ __forceinline__ f32x4 mfma16(bf16x8 a, bf16x8 b, f32x4 c) {
  return __builtin_amdgcn_mfma_f32_16x16x32_bf16(a, b, c, 0, 0, 0);
}

// ---------------------------------------------------------------------------
// fp32 -> bf16 convert (3 activations + 4 weights), grid.y selects tensor
// ---------------------------------------------------------------------------
__global__ __launch_bounds__(256) void cvt_bf16(
    const float* __restrict__ s0, const float* __restrict__ s1,
    const float* __restrict__ s2, const float* __restrict__ s3,
    const float* __restrict__ s4, const float* __restrict__ s5,
    const float* __restrict__ s6, unsigned short* __restrict__ ws)
{
  int t = blockIdx.y;
  const float* s; unsigned off; int n8;
  switch (t) {
    case 0:  s = s0; off = OFF_XV; n8 = 524288; break;
    case 1:  s = s1; off = OFF_XK; n8 = 524288; break;
    case 2:  s = s2; off = OFF_XQ; n8 = 524288; break;
    case 3:  s = s3; off = OFF_WV; n8 = 131072; break;
    case 4:  s = s4; off = OFF_WK; n8 = 131072; break;
    case 5:  s = s5; off = OFF_WQ; n8 = 131072; break;
    default: s = s6; off = OFF_WO; n8 = 131072; break;
  }
  const float4* sf = (const float4*)s;
  unsigned short* d = ws + off;
  for (int i = blockIdx.x * 256 + threadIdx.x; i < n8; i += gridDim.x * 256) {
    float4 a = sf[2 * i], b = sf[2 * i + 1];
    uint4 o;
    o.x = (unsigned)f2bf(a.x) | ((unsigned)f2bf(a.y) << 16);
    o.y = (unsigned)f2bf(a.z) | ((unsigned)f2bf(a.w) << 16);
    o.z = (unsigned)f2bf(b.x) | ((unsigned)f2bf(b.y) << 16);
    o.w = (unsigned)f2bf(b.z) | ((unsigned)f2bf(b.w) << 16);
    *(uint4*)&d[(size_t)i * 8] = o;
  }
}

// ---------------------------------------------------------------------------
// GEMM: C[m,n] = sum_k A[m,k] * W[n,k]   (A row-major [M][1024], W [N][1024])
// 128x128 tile, BK=32, 4 waves (2x2 of 64x64), double-buffered LDS,
// global_load_lds staging with bank-swizzle (chunk ^= (row>>1)&3, involution
// applied to the pre-swizzled global source AND the ds_read address).
// mode 0/1/2 = v/k/q projection (bf16 out, [B,H,S,D]); mode 3 = out-proj.
// ---------------------------------------------------------------------------
__global__ __launch_bounds__(256) void gemm_bf16(
    unsigned short* __restrict__ ws, float* __restrict__ dout,
    const float* __restrict__ bo, int mode_base)
{
  int mode = mode_base + blockIdx.z;
  const unsigned short* A;
  const unsigned short* W;
  if (mode == 0)      { A = ws + OFF_XV;  W = ws + OFF_WV; }
  else if (mode == 1) { A = ws + OFF_XK;  W = ws + OFF_WK; }
  else if (mode == 2) { A = ws + OFF_XQ;  W = ws + OFF_WQ; }
  else                { A = ws + OFF_ATT; W = ws + OFF_WO; }

  int tid = threadIdx.x;
  int lane = tid & 63;
  int wid = tid >> 6;
  int l15 = lane & 15, lg = lane >> 4;
  int wm = wid >> 1, wn = wid & 1;
  int m0 = blockIdx.y * 128, n0 = blockIdx.x * 128;
  int c0 = wid * 2;

  __shared__ unsigned short Ab[2][4096];
  __shared__ unsigned short Bb[2][4096];

  f32x4 acc[4][4];
#pragma unroll
  for (int i = 0; i < 4; ++i)
#pragma unroll
    for (int j = 0; j < 4; ++j) acc[i][j] = (f32x4)0.0f;

  // staging chunk geometry: c in [0,512), row = c>>2 (tile row), cs = c&3
  // (8-bf16 chunk within the 32-elem row).  source col pre-swizzled.
#pragma unroll
  for (int i = 0; i < 2; ++i) {
    int c = (c0 + i) * 64 + lane;
    int row = c >> 2, cs = c & 3;
    int sc = (cs ^ ((row >> 1) & 3)) * 8;
    async_cp16(A + (size_t)(m0 + row) * 1024 + sc, &Ab[0][(c0 + i) * 512]);
    async_cp16(W + (size_t)(n0 + row) * 1024 + sc, &Bb[0][(c0 + i) * 512]);
  }
  __syncthreads();

  for (int kt = 0; kt < 32; ++kt) {
    int cur = kt & 1;
    if (kt < 31) {
      int k0 = (kt + 1) * 32;
#pragma unroll
      for (int i = 0; i < 2; ++i) {
        int c = (c0 + i) * 64 + lane;
        int row = c >> 2, cs = c & 3;
        int sc = (cs ^ ((row >> 1) & 3)) * 8;
        async_cp16(A + (size_t)(m0 + row) * 1024 + k0 + sc, &Ab[cur ^ 1][(c0 + i) * 512]);
        async_cp16(W + (size_t)(n0 + row) * 1024 + k0 + sc, &Bb[cur ^ 1][(c0 + i) * 512]);
      }
    }
    bf16x8 af[4], bfr[4];
#pragma unroll
    for (int mf = 0; mf < 4; ++mf) {
      int ar = wm * 64 + mf * 16 + l15;
      af[mf] = *(const bf16x8*)&Ab[cur][ar * 32 + (lg ^ ((ar >> 1) & 3)) * 8];
    }
#pragma unroll
    for (int nf = 0; nf < 4; ++nf) {
      int br = wn * 64 + nf * 16 + l15;
      bfr[nf] = *(const bf16x8*)&Bb[cur][br * 32 + (lg ^ ((br >> 1) & 3)) * 8];
    }
#pragma unroll
    for (int mf = 0; mf < 4; ++mf)
#pragma unroll
      for (int nf = 0; nf < 4; ++nf)
        acc[mf][nf] = mfma16(af[mf], bfr[nf], acc[mf][nf]);
    __syncthreads();
  }

  if (mode < 3) {
    unsigned short* outp = ws + OFF_VB + (unsigned)mode * 4194304u;
    // q: fold 1/sqrt(D) * log2(e) so attention softmax runs in exp2 domain
    float scale = (mode == 2) ? 0.18033688011112042f : 1.0f;
#pragma unroll
    for (int mf = 0; mf < 4; ++mf)
#pragma unroll
      for (int nf = 0; nf < 4; ++nf)
#pragma unroll
        for (int r = 0; r < 4; ++r) {
          int token = m0 + wm * 64 + mf * 16 + lg * 4 + r;
          int col   = n0 + wn * 64 + nf * 16 + l15;
          // [B,H,S,D]
          size_t o = (((size_t)(token >> 11) * NHEAD + (col >> 6)) * SEQ
                      + (token & 2047)) * HDIM + (col & 63);
          outp[o] = f2bf(acc[mf][nf][r] * scale);
        }
  } else {
#pragma unroll
    for (int nf = 0; nf < 4; ++nf) {
      int col = n0 + wn * 64 + nf * 16 + l15;
      float bias = bo[col];
#pragma unroll
      for (int mf = 0; mf < 4; ++mf)
#pragma unroll
        for (int r = 0; r < 4; ++r) {
          int token = m0 + wm * 64 + mf * 16 + lg * 4 + r;
          dout[(size_t)token * EMB + col] = acc[mf][nf][r] + bias;
        }
    }
  }
}

// ---------------------------------------------------------------------------
// V [BH][S][D] -> VT [BH][D][S]  (64x64 tiles through LDS)
// ---------------------------------------------------------------------------
__global__ __launch_bounds__(256) void vtrans(
    const unsigned short* __restrict__ vsrc, unsigned short* __restrict__ vdst)
{
  __shared__ unsigned short T[64][72];
  int tid = threadIdx.x;
  int bh = blockIdx.y;
  int s0 = blockIdx.x * 64;
  const unsigned short* v = vsrc + (size_t)bh * SEQ * HDIM;
  unsigned short* o = vdst + (size_t)bh * HDIM * SEQ;

  int r = tid >> 2, cq = tid & 3;
  const uint4* src = (const uint4*)&v[(size_t)(s0 + r) * HDIM + cq * 16];
  uint4 d0 = src[0], d1 = src[1];
  *(uint4*)&T[r][cq * 16]     = d0;
  *(uint4*)&T[r][cq * 16 + 8] = d1;
  __syncthreads();

  int d = tid >> 2, sc = tid & 3;
  uint4 t4[2];
  unsigned short* tmp = (unsigned short*)t4;
#pragma unroll
  for (int j = 0; j < 16; ++j) tmp[j] = T[sc * 16 + j][d];
  *(uint4*)&o[(size_t)d * SEQ + s0 + sc * 16]     = t4[0];
  *(uint4*)&o[(size_t)d * SEQ + s0 + sc * 16 + 8] = t4[1];
}

// ---------------------------------------------------------------------------
// Flash attention fwd.  1024 blocks 1-D, bh-major (bh = bid & 31) so the
// round-robin block->XCD map gives each XCD ~4 heads (2 MB K/V -> L2-fits).
// 256 thr (4 waves), 64 q-rows/block, 16 q-rows/wave.  KVBLK=64, K/VT
// double-buffered LDS (XOR-swizzled via pre-swizzled global source).
// LDS = 40960 B exactly -> 4 blocks/CU.  Online softmax in exp2 domain,
// per-lane partial denominator, defer-max (THR=8).  setprio around MFMA.
// ---------------------------------------------------------------------------
__global__ __launch_bounds__(256) void attn_fwd(unsigned short* __restrict__ ws)
{
  int tid = threadIdx.x, lane = tid & 63, wid = tid >> 6;
  int l15 = lane & 15, lg = lane >> 4;
  int bh = blockIdx.x & 31;
  int q0 = (blockIdx.x >> 5) * 64;

  const unsigned short* qb = ws + OFF_QB + (size_t)bh * SEQ * HDIM;
  const unsigned short* kb = ws + OFF_KB + (size_t)bh * SEQ * HDIM;
  const unsigned short* vt = ws + OFF_VT + (size_t)bh * HDIM * SEQ;
  unsigned short* att = ws + OFF_ATT;

  __shared__ unsigned short Kb[2][4096];   // [64 kv][64 d], swizzled
  __shared__ unsigned short Vb[2][4096];   // [64 d][64 kv], swizzled
  __shared__ unsigned short Pb[4][1024];   // per-wave [16 q][64 kv], chunk-XOR swz

  // Q fragments: A-operand rows = wid*16 + l15, k = kk*32 + lg*8
  bf16x8 qf[2];
#pragma unroll
  for (int kk = 0; kk < 2; ++kk)
    qf[kk] = *(const bf16x8*)
        &qb[(size_t)(q0 + wid * 16 + l15) * HDIM + kk * 32 + lg * 8];

  f32x4 O[4];
#pragma unroll
  for (int nf = 0; nf < 4; ++nf) O[nf] = (f32x4)0.0f;
  float mrow[4], lp[4];
#pragma unroll
  for (int r = 0; r < 4; ++r) { mrow[r] = -1e30f; lp[r] = 0.0f; }

  int c0 = wid * 2;
  auto stage = [&](int buf, int kv0) {
#pragma unroll
    for (int i = 0; i < 2; ++i) {
      int c = (c0 + i) * 64 + lane;
      int row = c >> 3, cs = c & 7;          // 8 chunks of 8 bf16 per 64-elem row
      int scol = (cs ^ (row & 7)) * 8;       // pre-swizzled source column
      async_cp16(kb + (size_t)(kv0 + row) * HDIM + scol, &Kb[buf][(c0 + i) * 512]);
      async_cp16(vt + (size_t)row * SEQ + kv0 + scol,     &Vb[buf][(c0 + i) * 512]);
    }
  };

  stage(0, 0);
  __syncthreads();

  for (int it = 0; it < 32; ++it) {
    int cur = it & 1;
    if (it < 31) stage(cur ^ 1, (it + 1) * 64);

    // ---- S = Q K^T  (per wave: 16 q-rows x 64 kv) ----
    f32x4 S[4];
#pragma unroll
    for (int nf = 0; nf < 4; ++nf) S[nf] = (f32x4)0.0f;
    __builtin_amdgcn_s_setprio(1);
#pragma unroll
    for (int kk = 0; kk < 2; ++kk) {
#pragma unroll
      for (int nf = 0; nf < 4; ++nf) {
        int row = nf * 16 + l15;                                  // kv row
        int off = (row * 128 + kk * 64 + lg * 16) ^ ((row & 7) << 4);
        bf16x8 kf = *(const bf16x8*)((const char*)&Kb[cur][0] + off);
        S[nf] = mfma16(qf[kk], kf, S[nf]);
      }
    }
    __builtin_amdgcn_s_setprio(0);

    // ---- online softmax (exp2 domain; row (lg,r), lanes l15) ----
    float lmax[4];
    bool need = false;
#pragma unroll
    for (int r = 0; r < 4; ++r) {
      float rx = fmaxf(fmaxf(S[0][r], S[1][r]), fmaxf(S[2][r], S[3][r]));
      lmax[r] = rx;
      need = need || (rx > mrow[r] + 8.0f);
    }
    if (__any((int)need)) {
      // running max grew somewhere: full reduce + rescale (rare after tile 0)
#pragma unroll
      for (int r = 0; r < 4; ++r) {
        float rx = lmax[r];
        rx = fmaxf(rx, __shfl_xor(rx, 1));
        rx = fmaxf(rx, __shfl_xor(rx, 2));
        rx = fmaxf(rx, __shfl_xor(rx, 4));
        rx = fmaxf(rx, __shfl_xor(rx, 8));
        float mold = mrow[r];
        float mnew = fmaxf(mold, rx);
        float scl = __builtin_amdgcn_exp2f(mold - mnew);
        mrow[r] = mnew;
        lp[r] *= scl;
#pragma unroll
        for (int nf = 0; nf < 4; ++nf) O[nf][r] *= scl;
      }
    }
    // common path: P = exp2(S - m), lane-local partial denominator
#pragma unroll
    for (int r = 0; r < 4; ++r) {
      float m = mrow[r];
      float s0 = __builtin_amdgcn_exp2f(S[0][r] - m);
      float s1 = __builtin_amdgcn_exp2f(S[1][r] - m);
      float s2 = __builtin_amdgcn_exp2f(S[2][r] - m);
      float s3 = __builtin_amdgcn_exp2f(S[3][r] - m);
      S[0][r] = s0; S[1][r] = s1; S[2][r] = s2; S[3][r] = s3;
      lp[r] += (s0 + s1) + (s2 + s3);
    }

    // ---- P -> LDS (bf16), per-wave [16][64] with chunk-XOR swizzle ----
    unsigned short* pw = &Pb[wid][0];
#pragma unroll
    for (int nf = 0; nf < 4; ++nf)
#pragma unroll
      for (int r = 0; r < 4; ++r) {
        int m = lg * 4 + r;                       // P row (q)
        int chunk = (nf * 2 + (l15 >> 3)) ^ (m & 7);
        pw[m * 64 + chunk * 8 + (l15 & 7)] = f2bf(S[nf][r]);
      }

    // ---- O += P V ----
    __builtin_amdgcn_s_setprio(1);
#pragma unroll
    for (int kk = 0; kk < 2; ++kk) {
      int chunk = (kk * 4 + lg) ^ (l15 & 7);
      bf16x8 pf = *(const bf16x8*)&pw[l15 * 64 + chunk * 8];
#pragma unroll
      for (int nf = 0; nf < 4; ++nf) {
        int d = nf * 16 + l15;
        int off = (d * 128 + kk * 64 + lg * 16) ^ ((d & 7) << 4);
        bf16x8 vf = *(const bf16x8*)((const char*)&Vb[cur][0] + off);
        O[nf] = mfma16(pf, vf, O[nf]);
      }
    }
    __builtin_amdgcn_s_setprio(0);
    __syncthreads();
  }

  // ---- finalize: reduce lane-partial denominator once, store [B,S,E] ----
  int b = bh >> 4, h = bh & 15;
#pragma unroll
  for (int r = 0; r < 4; ++r) {
    float ps = lp[r];
    ps += __shfl_xor(ps, 1);
    ps += __shfl_xor(ps, 2);
    ps += __shfl_xor(ps, 4);
    ps += __shfl_xor(ps, 8);
    float inv = 1.0f / ps;
    int srow = q0 + wid * 16 + lg * 4 + r;
#pragma unroll
    for (int nf = 0; nf < 4; ++nf) {
      int e = h * 64 + nf * 16 + l15;
      att[((size_t)b * SEQ + srow) * EMB + e] = f2bf(O[nf][r] * inv);
    }
  }
}

// ---------------------------------------------------------------------------
extern "C" void kernel_launch(void* const* d_in, const int* in_sizes, int n_in,
                              void* d_out, int out_size, void* d_ws, size_t ws_size,
                              hipStream_t stream)
{
  const float* value = (const float*)d_in[0];
  const float* key_t = (const float*)d_in[1];
  const float* query = (const float*)d_in[2];
  const float* Wv = (const float*)d_in[3];
  const float* Wk = (const float*)d_in[4];
  const float* Wq = (const float*)d_in[5];
  const float* Wo = (const float*)d_in[6];
  const float* bo = (const float*)d_in[7];
  unsigned short* ws = (unsigned short*)d_ws;
  float* out = (float*)d_out;

  cvt_bf16<<<dim3(512, 7), 256, 0, stream>>>(value, key_t, query, Wv, Wk, Wq, Wo, ws);
  gemm_bf16<<<dim3(8, 32, 3), 256, 0, stream>>>(ws, out, bo, 0);      // q,k,v proj
  vtrans<<<dim3(32, 32), 256, 0, stream>>>(ws + OFF_VB, ws + OFF_VT); // V -> V^T
  attn_fwd<<<1024, 256, 0, stream>>>(ws);                              // flash attn
  gemm_bf16<<<dim3(8, 32, 1), 256, 0, stream>>>(ws, out, bo, 3);      // out proj
}

// Round 10
// 219.838 us; speedup vs baseline: 1.2686x; 1.2686x over previous
//
#include <hip/hip_runtime.h>

// ---------------------------------------------------------------------------
// MultiHeadAttention fwd: B=2, S=2048, E=1024, H=16, D=64, fp32 in/out,
// bf16 MFMA compute (fp32 accum), exp2-domain online softmax.
// Attention uses swapped QK^T (S^T = K·Q^T fragments) with a pi-permuted K
// row order in LDS so P stays entirely in registers (no P LDS round-trip).
// ---------------------------------------------------------------------------

#define SEQ   2048
#define EMB   1024
#define NHEAD 16
#define HDIM  64
#define NTOK  4096   // B*S

typedef __attribute__((ext_vector_type(8))) __bf16 bf16x8;
typedef __attribute__((ext_vector_type(4))) float  f32x4;

// workspace layout (ushort elements). top = 29360128 ushorts = 56 MB.
#define OFF_XV  0u          // [4096][1024] bf16 (value)
#define OFF_XK  4194304u
#define OFF_XQ  8388608u
#define OFF_WV  12582912u   // [1024][1024] bf16
#define OFF_WK  13631488u
#define OFF_WQ  14680064u
#define OFF_WO  15728640u
#define OFF_VT  16777216u   // [BH][D][S] bf16 (V^T, written by gemm mode 0)
#define OFF_KB  20971520u   // [BH][S][D] bf16
#define OFF_QB  25165824u   // [BH][S][D] bf16, pre-scaled by 0.125*log2(e)
#define OFF_ATT 0u          // attn out [B,S,E] — aliases XV (dead after projections)

typedef __attribute__((address_space(1))) void g_void;
typedef __attribute__((address_space(3))) void l_void;

__device__ __forceinline__ void async_cp16(const void* g, void* l) {
  // 16B per lane, dest = wave-uniform base + lane*16 (linear LDS, rule #21).
  __builtin_amdgcn_global_load_lds((g_void*)(void*)g, (l_void*)l, 16, 0, 0);
}

__device__ __forceinline__ unsigned short f2bf(float f) {
  __bf16 h = (__bf16)f;
  return __builtin_bit_cast(unsigned short, h);
}

__device__ __forceinline__ f32x4 mfma16(bf16x8 a, bf16x8 b, f32x4 c) {
  return __builtin_amdgcn_mfma_f32_16x16x32_bf16(a, b, c, 0, 0, 0);
}

// ---------------------------------------------------------------------------
// fp32 -> bf16 convert (3 activations + 4 weights), grid.y selects tensor
// ---------------------------------------------------------------------------
__global__ __launch_bounds__(256) void cvt_bf16(
    const float* __restrict__ s0, const float* __restrict__ s1,
    const float* __restrict__ s2, const float* __restrict__ s3,
    const float* __restrict__ s4, const float* __restrict__ s5,
    const float* __restrict__ s6, unsigned short* __restrict__ ws)
{
  int t = blockIdx.y;
  const float* s; unsigned off; int n8;
  switch (t) {
    case 0:  s = s0; off = OFF_XV; n8 = 524288; break;
    case 1:  s = s1; off = OFF_XK; n8 = 524288; break;
    case 2:  s = s2; off = OFF_XQ; n8 = 524288; break;
    case 3:  s = s3; off = OFF_WV; n8 = 131072; break;
    case 4:  s = s4; off = OFF_WK; n8 = 131072; break;
    case 5:  s = s5; off = OFF_WQ; n8 = 131072; break;
    default: s = s6; off = OFF_WO; n8 = 131072; break;
  }
  const float4* sf = (const float4*)s;
  unsigned short* d = ws + off;
  for (int i = blockIdx.x * 256 + threadIdx.x; i < n8; i += gridDim.x * 256) {
    float4 a = sf[2 * i], b = sf[2 * i + 1];
    uint4 o;
    o.x = (unsigned)f2bf(a.x) | ((unsigned)f2bf(a.y) << 16);
    o.y = (unsigned)f2bf(a.z) | ((unsigned)f2bf(a.w) << 16);
    o.z = (unsigned)f2bf(b.x) | ((unsigned)f2bf(b.y) << 16);
    o.w = (unsigned)f2bf(b.z) | ((unsigned)f2bf(b.w) << 16);
    *(uint4*)&d[(size_t)i * 8] = o;
  }
}

// ---------------------------------------------------------------------------
// GEMM: C[m,n] = sum_k A[m,k] * W[n,k]   (A row-major [M][1024], W [N][1024])
// 128x128 tile, BK=32, 4 waves (2x2 of 64x64), double-buffered LDS,
// global_load_lds staging with bank-swizzle.  Outputs:
//   mode 0: V^T [BH][D][S] bf16 (tile transposed through LDS, coalesced along S)
//   mode 1/2: K/Q [B,H,S,D] bf16, transposed through LDS for coalesced stores
//             (q pre-scaled by 0.125*log2e)
//   mode 3: out-proj fp32 + bias -> d_out
// ---------------------------------------------------------------------------
__global__ __launch_bounds__(256) void gemm_bf16(
    unsigned short* __restrict__ ws, float* __restrict__ dout,
    const float* __restrict__ bo, int mode_base)
{
  int mode = mode_base + blockIdx.z;
  const unsigned short* A;
  const unsigned short* W;
  if (mode == 0)      { A = ws + OFF_XV;  W = ws + OFF_WV; }
  else if (mode == 1) { A = ws + OFF_XK;  W = ws + OFF_WK; }
  else if (mode == 2) { A = ws + OFF_XQ;  W = ws + OFF_WQ; }
  else                { A = ws + OFF_ATT; W = ws + OFF_WO; }

  int tid = threadIdx.x;
  int lane = tid & 63;
  int wid = tid >> 6;
  int l15 = lane & 15, lg = lane >> 4;
  int wm = wid >> 1, wn = wid & 1;
  int m0 = blockIdx.y * 128, n0 = blockIdx.x * 128;
  int c0 = wid * 2;

  __shared__ unsigned short SM[16384];              // Ab | Bb, reused as T[128][128]
  unsigned short (*Ab)[4096] = (unsigned short(*)[4096])SM;
  unsigned short (*Bb)[4096] = (unsigned short(*)[4096])(SM + 8192);

  f32x4 acc[4][4];
#pragma unroll
  for (int i = 0; i < 4; ++i)
#pragma unroll
    for (int j = 0; j < 4; ++j) acc[i][j] = (f32x4)0.0f;

  // staging chunk geometry: c in [0,512), row = c>>2 (tile row), cs = c&3
  // (8-bf16 chunk within the 32-elem row).  source col pre-swizzled.
#pragma unroll
  for (int i = 0; i < 2; ++i) {
    int c = (c0 + i) * 64 + lane;
    int row = c >> 2, cs = c & 3;
    int sc = (cs ^ ((row >> 1) & 3)) * 8;
    async_cp16(A + (size_t)(m0 + row) * 1024 + sc, &Ab[0][(c0 + i) * 512]);
    async_cp16(W + (size_t)(n0 + row) * 1024 + sc, &Bb[0][(c0 + i) * 512]);
  }
  __syncthreads();

  for (int kt = 0; kt < 32; ++kt) {
    int cur = kt & 1;
    if (kt < 31) {
      int k0 = (kt + 1) * 32;
#pragma unroll
      for (int i = 0; i < 2; ++i) {
        int c = (c0 + i) * 64 + lane;
        int row = c >> 2, cs = c & 3;
        int sc = (cs ^ ((row >> 1) & 3)) * 8;
        async_cp16(A + (size_t)(m0 + row) * 1024 + k0 + sc, &Ab[cur ^ 1][(c0 + i) * 512]);
        async_cp16(W + (size_t)(n0 + row) * 1024 + k0 + sc, &Bb[cur ^ 1][(c0 + i) * 512]);
      }
    }
    bf16x8 af[4], bfr[4];
#pragma unroll
    for (int mf = 0; mf < 4; ++mf) {
      int ar = wm * 64 + mf * 16 + l15;
      af[mf] = *(const bf16x8*)&Ab[cur][ar * 32 + (lg ^ ((ar >> 1) & 3)) * 8];
    }
#pragma unroll
    for (int nf = 0; nf < 4; ++nf) {
      int br = wn * 64 + nf * 16 + l15;
      bfr[nf] = *(const bf16x8*)&Bb[cur][br * 32 + (lg ^ ((br >> 1) & 3)) * 8];
    }
    __builtin_amdgcn_s_setprio(1);
#pragma unroll
    for (int mf = 0; mf < 4; ++mf)
#pragma unroll
      for (int nf = 0; nf < 4; ++nf)
        acc[mf][nf] = mfma16(af[mf], bfr[nf], acc[mf][nf]);
    __builtin_amdgcn_s_setprio(0);
    __syncthreads();
  }

  if (mode == 0) {
    // V^T epilogue: acc -> LDS transposed (XOR-swizzled), then coalesced
    // stores along S.  col-local c = output row d (within 2 heads), s = token.
#pragma unroll
    for (int mf = 0; mf < 4; ++mf)
#pragma unroll
      for (int nf = 0; nf < 4; ++nf)
#pragma unroll
        for (int r = 0; r < 4; ++r) {
          int c = wn * 64 + nf * 16 + l15;
          int s = wm * 64 + mf * 16 + lg * 4 + r;
          SM[c * 128 + (s ^ ((c & 7) << 3))] = f2bf(acc[mf][nf][r]);
        }
    __syncthreads();
    int sidx = tid & 15, cbase = tid >> 4;
    size_t b = (size_t)(m0 >> 11);
#pragma unroll
    for (int i = 0; i < 8; ++i) {
      int c = i * 16 + cbase;
      int h = (n0 >> 6) + (c >> 6);
      uint4 v = *(const uint4*)&SM[c * 128 + ((sidx ^ (c & 7)) * 8)];
      size_t bh = b * NHEAD + h;
      *(uint4*)&ws[OFF_VT + (bh * HDIM + (c & 63)) * SEQ + (m0 & 2047) + sidx * 8] = v;
    }
  } else if (mode < 3) {
    // K/Q epilogue: acc -> LDS [token][col] (XOR-swizzled), then coalesced
    // 16B stores: 16 lanes per token row, two 128B runs (one per head).
    unsigned short* outp = ws + ((mode == 1) ? OFF_KB : OFF_QB);
    float scale = (mode == 2) ? 0.18033688011112042f : 1.0f; // 1/8*log2(e)
#pragma unroll
    for (int mf = 0; mf < 4; ++mf)
#pragma unroll
      for (int nf = 0; nf < 4; ++nf)
#pragma unroll
        for (int r = 0; r < 4; ++r) {
          int s = wm * 64 + mf * 16 + lg * 4 + r;
          int c = wn * 64 + nf * 16 + l15;
          SM[s * 128 + (c ^ ((s & 7) << 3))] = f2bf(acc[mf][nf][r] * scale);
        }
    __syncthreads();
    int l = tid & 15, rb = tid >> 4;
    int half = l >> 3, j = l & 7;
    size_t b = (size_t)(m0 >> 11);
#pragma unroll
    for (int i = 0; i < 8; ++i) {
      int s = i * 16 + rb;
      uint4 v = *(const uint4*)&SM[s * 128 + half * 64 + ((j ^ (s & 7)) * 8)];
      int h = (n0 >> 6) + half;
      size_t bh = b * NHEAD + h;
      *(uint4*)&outp[(bh * SEQ + ((m0 + s) & 2047)) * HDIM + j * 8] = v;
    }
  } else {
#pragma unroll
    for (int nf = 0; nf < 4; ++nf) {
      int col = n0 + wn * 64 + nf * 16 + l15;
      float bias = bo[col];
#pragma unroll
      for (int mf = 0; mf < 4; ++mf)
#pragma unroll
        for (int r = 0; r < 4; ++r) {
          int token = m0 + wm * 64 + mf * 16 + lg * 4 + r;
          dout[(size_t)token * EMB + col] = acc[mf][nf][r] + bias;
        }
    }
  }
}

// ---------------------------------------------------------------------------
// Flash attention fwd.  512 blocks 1-D, bh-major (bh = bid & 31).
// 256 thr (4 waves), 128 q-rows/block, 32 q-rows/wave.  KVBLK=64.
// Swapped QK^T: S^T = mfma(A=K, B=Q) so lane (l15,lg) owns q = mf*16+l15 and
// holds S for kv = pi(nf,lg,r) = 32(nf&1)+8lg+4(nf>>1)+r.  K is staged with
// pi-permuted rows, so each lane's 16 S values are exactly its PV A-fragment
// (kv = kk*32+lg*8+j) -> P stays in registers.  V^T staging unchanged.
// Online softmax in exp2 domain, lane-partial denominator, defer-max (THR=8):
// zero cross-lane ops on the common path.  LDS 32 KB (K+V dbuf only).
// ---------------------------------------------------------------------------
__global__ __launch_bounds__(256) void attn_fwd(unsigned short* __restrict__ ws)
{
  int tid = threadIdx.x, lane = tid & 63, wid = tid >> 6;
  int l15 = lane & 15, lg = lane >> 4;
  int bh = blockIdx.x & 31;
  int q0 = (blockIdx.x >> 5) * 128;

  const unsigned short* qb = ws + OFF_QB + (size_t)bh * SEQ * HDIM;
  const unsigned short* kb = ws + OFF_KB + (size_t)bh * SEQ * HDIM;
  const unsigned short* vt = ws + OFF_VT + (size_t)bh * HDIM * SEQ;
  unsigned short* att = ws + OFF_ATT;

  __shared__ unsigned short Kb[2][4096];   // [64 kv-pos (pi-permuted)][64 d], swz
  __shared__ unsigned short Vb[2][4096];   // [64 d][64 kv], swz

  // Q fragments (B-operand): col = q = wid*32 + mf*16 + l15, k = kk*32 + lg*8
  bf16x8 qf[2][2];
#pragma unroll
  for (int mf = 0; mf < 2; ++mf)
#pragma unroll
    for (int kk = 0; kk < 2; ++kk)
      qf[mf][kk] = *(const bf16x8*)
          &qb[(size_t)(q0 + wid * 32 + mf * 16 + l15) * HDIM + kk * 32 + lg * 8];

  f32x4 O[2][4];
#pragma unroll
  for (int mf = 0; mf < 2; ++mf)
#pragma unroll
    for (int nf = 0; nf < 4; ++nf) O[mf][nf] = (f32x4)0.0f;
  float mrow[2], lp[2];
#pragma unroll
  for (int mf = 0; mf < 2; ++mf) { mrow[mf] = -1e30f; lp[mf] = 0.0f; }

  int c0 = wid * 2;
  auto stage = [&](int buf, int kv0) {
#pragma unroll
    for (int i = 0; i < 2; ++i) {
      int c = (c0 + i) * 64 + lane;
      int p = c >> 3, cs = c & 7;            // LDS row p, 8-bf16 chunk cs
      int scol = (cs ^ (p & 7)) * 8;         // pre-swizzled source column
      // K: pi row permutation (bit swap of p's bits 4<->5 group structure)
      int kpi = ((p >> 4) & 1) * 32 + ((p >> 2) & 3) * 8 + (p >> 5) * 4 + (p & 3);
      async_cp16(kb + (size_t)(kv0 + kpi) * HDIM + scol, &Kb[buf][(c0 + i) * 512]);
      async_cp16(vt + (size_t)p * SEQ + kv0 + scol,       &Vb[buf][(c0 + i) * 512]);
    }
  };

  stage(0, 0);
  __syncthreads();

  for (int it = 0; it < 32; ++it) {
    int cur = it & 1;
    if (it < 31) stage(cur ^ 1, (it + 1) * 64);

    // ---- S^T = K . Q  (A = K pi-rows, B = Q) ----
    f32x4 S[2][4];
#pragma unroll
    for (int mf = 0; mf < 2; ++mf)
#pragma unroll
      for (int nf = 0; nf < 4; ++nf) S[mf][nf] = (f32x4)0.0f;
    __builtin_amdgcn_s_setprio(1);
#pragma unroll
    for (int kk = 0; kk < 2; ++kk) {
#pragma unroll
      for (int nf = 0; nf < 4; ++nf) {
        int p = nf * 16 + l15;                                  // LDS kv-pos row
        int off = (p * 128 + kk * 64 + lg * 16) ^ ((p & 7) << 4);
        bf16x8 kf = *(const bf16x8*)((const char*)&Kb[cur][0] + off);
        S[0][nf] = mfma16(kf, qf[0][kk], S[0][nf]);
        S[1][nf] = mfma16(kf, qf[1][kk], S[1][nf]);
      }
    }
    __builtin_amdgcn_s_setprio(0);
    // lane (l15,lg) now holds S[q = mf*16+l15][kv = 32(nf&1)+8lg+4(nf>>1)+r]

    // ---- online softmax (exp2 domain), lane-local ----
    float lmax[2];
    bool need = false;
#pragma unroll
    for (int mf = 0; mf < 2; ++mf) {
      float rx = S[mf][0][0];
#pragma unroll
      for (int nf = 0; nf < 4; ++nf)
#pragma unroll
        for (int r = 0; r < 4; ++r) rx = fmaxf(rx, S[mf][nf][r]);
      lmax[mf] = rx;
      need = need || (rx > mrow[mf] + 8.0f);
    }
    if (__any((int)need)) {
      float scl[2];
#pragma unroll
      for (int mf = 0; mf < 2; ++mf) {
        float rx = lmax[mf];
        rx = fmaxf(rx, __shfl_xor(rx, 16));
        rx = fmaxf(rx, __shfl_xor(rx, 32));   // full row max (4 lanes share q)
        float mold = mrow[mf];
        float mnew = fmaxf(mold, rx);
        scl[mf] = __builtin_amdgcn_exp2f(mold - mnew);
        mrow[mf] = mnew;
        lp[mf] *= scl[mf];
      }
      // O rows live at q = mf*16 + lg*4 + r -> fetch scl from lane lg*4+r
#pragma unroll
      for (int mf = 0; mf < 2; ++mf)
#pragma unroll
        for (int r = 0; r < 4; ++r) {
          float f = __shfl(scl[mf], lg * 4 + r);
#pragma unroll
          for (int nf = 0; nf < 4; ++nf) O[mf][nf][r] *= f;
        }
    }
    // P = exp2(S - m); lane-partial denominator (no cross-lane)
#pragma unroll
    for (int mf = 0; mf < 2; ++mf) {
      float m = mrow[mf];
      float acc0 = 0.0f, acc1 = 0.0f;
#pragma unroll
      for (int nf = 0; nf < 4; ++nf)
#pragma unroll
        for (int r = 0; r < 4; ++r) {
          float e = __builtin_amdgcn_exp2f(S[mf][nf][r] - m);
          S[mf][nf][r] = e;
          if (r & 1) acc1 += e; else acc0 += e;
        }
      lp[mf] += acc0 + acc1;
    }

    // ---- O += P V : P already lane-resident as the PV A-fragment ----
    __builtin_amdgcn_s_setprio(1);
#pragma unroll
    for (int kk = 0; kk < 2; ++kk) {
      bf16x8 pa[2];
#pragma unroll
      for (int mf = 0; mf < 2; ++mf)
#pragma unroll
        for (int j = 0; j < 4; ++j) {
          pa[mf][j]     = (__bf16)S[mf][kk][j];       // kv = 32kk+8lg+j
          pa[mf][4 + j] = (__bf16)S[mf][2 + kk][j];   // kv = 32kk+8lg+4+j
        }
#pragma unroll
      for (int nf = 0; nf < 4; ++nf) {
        int d = nf * 16 + l15;
        int off = (d * 128 + kk * 64 + lg * 16) ^ ((d & 7) << 4);
        bf16x8 vf = *(const bf16x8*)((const char*)&Vb[cur][0] + off);
        O[0][nf] = mfma16(pa[0], vf, O[0][nf]);
        O[1][nf] = mfma16(pa[1], vf, O[1][nf]);
      }
    }
    __builtin_amdgcn_s_setprio(0);
    __syncthreads();
  }

  // ---- finalize: reduce lane-partial denominator, store [B,S,E] bf16 ----
  int b = bh >> 4, h = bh & 15;
  float lr[2];
#pragma unroll
  for (int mf = 0; mf < 2; ++mf) {
    float s = lp[mf];
    s += __shfl_xor(s, 16);
    s += __shfl_xor(s, 32);
    lr[mf] = s;                     // row sum for q = mf*16 + l15
  }
#pragma unroll
  for (int mf = 0; mf < 2; ++mf)
#pragma unroll
    for (int r = 0; r < 4; ++r) {
      float inv = 1.0f / __shfl(lr[mf], lg * 4 + r);
      int srow = q0 + wid * 32 + mf * 16 + lg * 4 + r;
#pragma unroll
      for (int nf = 0; nf < 4; ++nf) {
        int e = h * 64 + nf * 16 + l15;
        att[((size_t)b * SEQ + srow) * EMB + e] = f2bf(O[mf][nf][r] * inv);
      }
    }
}

// ---------------------------------------------------------------------------
extern "C" void kernel_launch(void* const* d_in, const int* in_sizes, int n_in,
                              void* d_out, int out_size, void* d_ws, size_t ws_size,
                              hipStream_t stream)
{
  const float* value = (const float*)d_in[0];
  const float* key_t = (const float*)d_in[1];
  const float* query = (const float*)d_in[2];
  const float* Wv = (const float*)d_in[3];
  const float* Wk = (const float*)d_in[4];
  const float* Wq = (const float*)d_in[5];
  const float* Wo = (const float*)d_in[6];
  const float* bo = (const float*)d_in[7];
  unsigned short* ws = (unsigned short*)d_ws;
  float* out = (float*)d_out;

  cvt_bf16<<<dim3(512, 7), 256, 0, stream>>>(value, key_t, query, Wv, Wk, Wq, Wo, ws);
  gemm_bf16<<<dim3(8, 32, 3), 256, 0, stream>>>(ws, out, bo, 0);   // v,k,q proj (+V^T)
  attn_fwd<<<512, 256, 0, stream>>>(ws);                            // flash attn
  gemm_bf16<<<dim3(8, 32, 1), 256, 0, stream>>>(ws, out, bo, 3);   // out proj
}